// Round 1
// baseline (272.426 us; speedup 1.0000x reference)
//
#include <hip/hip_runtime.h>
#include <math.h>

// EMA along T: y[0]=x[0]; y[t] = (1-a)*y[t-1] + a*x[t], a=0.01.
// 3-phase chunked scan: (1) per-chunk local ends, (2) tiny K-scan turning
// ends into per-chunk carry-ins (in-place, 4 MB ws), (3) apply.
// CHUNK=32 -> K=256 -> 2048 blocks -> 16 waves/CU (vs 4 before): the two
// streaming phases become BW-bound instead of latency-bound.

namespace {
constexpr int B = 8;
constexpr int T = 8192;
constexpr int C = 512;
constexpr float ALPHA = 0.01f;
constexpr float DECAY = 1.0f - ALPHA;   // 0.99
constexpr int S4 = C / 4;               // float4 per timestep = 128
constexpr int TPB = S4;                 // 128 threads, 4 channels each

typedef float f32x4 __attribute__((ext_vector_type(4)));

__device__ __forceinline__ void ema_step(float4& y, const float4 v) {
    y.x = DECAY * y.x + ALPHA * v.x;
    y.y = DECAY * y.y + ALPHA * v.y;
    y.z = DECAY * y.z + ALPHA * v.z;
    y.w = DECAY * y.w + ALPHA * v.w;
}
}

// Phase 1: per-chunk local EMA end-state. k==0 starts from the true init
// (y_pre = x[0] => y[0] = 0.99*x0 + 0.01*x0 = x0), so ends[0] is the TRUE
// state S_0; k>0 chunks start from 0 and produce local sums L_k.
template <int CHUNK>
__global__ __launch_bounds__(TPB) void ema_ends(const float* __restrict__ x,
                                                float* __restrict__ ends) {
    constexpr int K = T / CHUNK;
    const int k = blockIdx.x;
    const int b = blockIdx.y;
    const int tid = threadIdx.x;
    const float4* xp = reinterpret_cast<const float4*>(x) +
                       (size_t)(b * T + k * CHUNK) * S4 + tid;
    float4 y;
    if (k == 0) {
        y = xp[0];
    } else {
        y = make_float4(0.f, 0.f, 0.f, 0.f);
    }
#pragma unroll 8
    for (int t = 0; t < CHUNK; ++t) {
        float4 v = xp[(size_t)t * S4];
        ema_step(y, v);
    }
    reinterpret_cast<float4*>(ends)[(size_t)(b * K + k) * S4 + tid] = y;
}

// Phase 2: in-place K-scan of ends -> carry-ins.
// On entry slot m holds L_m (slot 0 holds S_0). S_m = dC * S_{m-1} + L_m.
// On exit slot m (m>=1) holds carry_in[m] = S_{m-1}; slot 0 is unused after.
// Tiny kernel: B blocks x 128 threads; loads prefetch ahead of the short
// dependent FMA chain, ~few us total.
template <int CHUNK>
__global__ __launch_bounds__(TPB) void ema_carry(float* ends, float dC) {
    constexpr int K = T / CHUNK;
    const int b = blockIdx.x;
    const int tid = threadIdx.x;
    float4* ep = reinterpret_cast<float4*>(ends) + (size_t)b * K * S4 + tid;
    float4 y = ep[0];  // S_0
#pragma unroll 8
    for (int m = 1; m < K; ++m) {
        float4 e = ep[(size_t)m * S4];   // L_m (read before overwrite)
        ep[(size_t)m * S4] = y;          // carry_in[m] = S_{m-1}
        y.x = dC * y.x + e.x;
        y.y = dC * y.y + e.y;
        y.z = dC * y.z + e.z;
        y.w = dC * y.w + e.w;
    }
}

// Phase 3: apply. Carry-in is a single L2-resident float4 read per thread.
// Nontemporal stores for out keep x resident in the 256 MB L3 (x is 128 MB
// and was just streamed through in phase 1), so the re-read can L3-hit.
template <int CHUNK>
__global__ __launch_bounds__(TPB) void ema_apply(const float* __restrict__ x,
                                                 const float* __restrict__ carry,
                                                 float* __restrict__ out) {
    constexpr int K = T / CHUNK;
    const int k = blockIdx.x;
    const int b = blockIdx.y;
    const int tid = threadIdx.x;
    const size_t base4 = (size_t)(b * T + k * CHUNK) * S4 + tid;
    const float4* xp = reinterpret_cast<const float4*>(x) + base4;
    float4* op = reinterpret_cast<float4*>(out) + base4;

    float4 y;
    if (k == 0) {
        y = xp[0];  // true init trick (see phase 1)
    } else {
        y = reinterpret_cast<const float4*>(carry)[(size_t)(b * K + k) * S4 + tid];
    }
#pragma unroll 8
    for (int t = 0; t < CHUNK; ++t) {
        float4 v = xp[(size_t)t * S4];
        ema_step(y, v);
        __builtin_nontemporal_store(*reinterpret_cast<const f32x4*>(&y),
                                    reinterpret_cast<f32x4*>(op + (size_t)t * S4));
    }
}

// Exact but slow fallback if ws is too small (one block per batch).
__global__ __launch_bounds__(TPB) void ema_seq_kernel(const float* __restrict__ x,
                                                      float* __restrict__ out) {
    const int b = blockIdx.x;
    const int tid = threadIdx.x;
    const float4* xp = reinterpret_cast<const float4*>(x) + (size_t)b * T * S4 + tid;
    float4* op = reinterpret_cast<float4*>(out) + (size_t)b * T * S4 + tid;
    float4 y = xp[0];
    for (int t = 0; t < T; ++t) {
        float4 v = xp[(size_t)t * S4];
        ema_step(y, v);
        op[(size_t)t * S4] = y;
    }
}

extern "C" void kernel_launch(void* const* d_in, const int* in_sizes, int n_in,
                              void* d_out, int out_size, void* d_ws, size_t ws_size,
                              hipStream_t stream) {
    (void)in_sizes; (void)n_in; (void)out_size;
    const float* x = reinterpret_cast<const float*>(d_in[0]);
    float* out = reinterpret_cast<float*>(d_out);

    constexpr int CH = 32;                 // K = 256, 2048 blocks/phase
    constexpr int KCH = T / CH;
    const size_t need = (size_t)B * KCH * C * sizeof(float);  // 4 MB

    constexpr int CH2 = 128;               // fallback geometry, 1 MB ws
    constexpr int KCH2 = T / CH2;
    const size_t need2 = (size_t)B * KCH2 * C * sizeof(float);

    if (ws_size >= need) {
        float* ends = reinterpret_cast<float*>(d_ws);
        const float dC = (float)pow((double)DECAY, (double)CH);
        ema_ends<CH><<<dim3(KCH, B), dim3(TPB), 0, stream>>>(x, ends);
        ema_carry<CH><<<dim3(B), dim3(TPB), 0, stream>>>(ends, dC);
        ema_apply<CH><<<dim3(KCH, B), dim3(TPB), 0, stream>>>(x, ends, out);
    } else if (ws_size >= need2) {
        float* ends = reinterpret_cast<float*>(d_ws);
        const float dC = (float)pow((double)DECAY, (double)CH2);
        ema_ends<CH2><<<dim3(KCH2, B), dim3(TPB), 0, stream>>>(x, ends);
        ema_carry<CH2><<<dim3(B), dim3(TPB), 0, stream>>>(ends, dC);
        ema_apply<CH2><<<dim3(KCH2, B), dim3(TPB), 0, stream>>>(x, ends, out);
    } else {
        ema_seq_kernel<<<dim3(B), dim3(TPB), 0, stream>>>(x, out);
    }
}

// Round 2
// 250.786 us; speedup vs baseline: 1.0863x; 1.0863x over previous
//
#include <hip/hip_runtime.h>
#include <math.h>

// EMA along T: y[0]=x[0]; y[t] = (1-a)*y[t-1] + a*x[t], a=0.01.
//
// 2-phase chunked scan exploiting EMA forgetting: decay^(64*32) ~ 1.2e-9,
// so a chunk's carry-in depends only on the previous W=32 chunk-end states
// (2048 timesteps of history). Phase 1 writes per-chunk local end states;
// phase 2 folds a BOUNDED 32-slot window of ends (L2-resident, fully
// parallel, no serial K-scan) and applies the chunk. No grid-wide
// serialization beyond the one kernel boundary.

namespace {
constexpr int B = 8;
constexpr int T = 8192;
constexpr int C = 512;
constexpr float ALPHA = 0.01f;
constexpr float DECAY = 1.0f - ALPHA;   // 0.99
constexpr int S4 = C / 4;               // float4 per timestep = 128
constexpr int TPB = S4;                 // 128 threads, 4 channels each
constexpr int CHUNK = 64;               // timesteps per block
constexpr int K = T / CHUNK;            // 128 chunks -> grid (128,8) = 1024 blocks
constexpr int W = 32;                   // carry lookback in chunks: 0.99^2048 ~ 1e-9

typedef float f32x4 __attribute__((ext_vector_type(4)));

__device__ __forceinline__ void ema_step(float4& y, const float4 v) {
    y.x = DECAY * y.x + ALPHA * v.x;
    y.y = DECAY * y.y + ALPHA * v.y;
    y.z = DECAY * y.z + ALPHA * v.z;
    y.w = DECAY * y.w + ALPHA * v.w;
}
}

// Phase 1: per-chunk local EMA end-state. k==0 starts from the true init
// (y_pre = x[0] => y[0] = 0.99*x0 + 0.01*x0 = x0), so ends[0] holds the TRUE
// running state S_0; k>0 chunks start from 0 and produce local sums L_k.
__global__ __launch_bounds__(TPB) void ema_ends(const float* __restrict__ x,
                                                float* __restrict__ ends) {
    const int k = blockIdx.x;
    const int b = blockIdx.y;
    const int tid = threadIdx.x;
    const float4* xp = reinterpret_cast<const float4*>(x) +
                       (size_t)(b * T + k * CHUNK) * S4 + tid;
    float4 y;
    if (k == 0) {
        y = xp[0];
    } else {
        y = make_float4(0.f, 0.f, 0.f, 0.f);
    }
#pragma unroll 8
    for (int t = 0; t < CHUNK; ++t) {
        float4 v = xp[(size_t)t * S4];
        ema_step(y, v);
    }
    reinterpret_cast<float4*>(ends)[(size_t)(b * K + k) * S4 + tid] = y;
}

// Phase 2: carry fold (bounded window) + apply.
// Exact carry: S_{k-1} = sum_{m=0}^{k-1} dC^{k-1-m} E_m  (E_0 = S_0 true).
// We keep only m >= k-W; dropped mass = dC^W * S_{k-W-1} ~ 6e-10. For k <= W
// the fold is EXACT (reaches m=0). Fold: 32 independent L2 loads feeding a
// 32-step FMA chain — uniform across blocks, no serialization.
__global__ __launch_bounds__(TPB) void ema_fold_apply(const float* __restrict__ x,
                                                      const float* __restrict__ ends,
                                                      float* __restrict__ out,
                                                      float dC) {
    const int k = blockIdx.x;
    const int b = blockIdx.y;
    const int tid = threadIdx.x;
    const size_t base4 = (size_t)(b * T + k * CHUNK) * S4 + tid;
    const float4* xp = reinterpret_cast<const float4*>(x) + base4;
    float4* op = reinterpret_cast<float4*>(out) + base4;

    float4 y;
    if (k == 0) {
        y = xp[0];  // true init trick (see phase 1)
    } else {
        y = make_float4(0.f, 0.f, 0.f, 0.f);
        const float4* ep = reinterpret_cast<const float4*>(ends) +
                           (size_t)b * K * S4 + tid;
        int m0 = k - W;
        if (m0 < 0) m0 = 0;
#pragma unroll 8
        for (int m = m0; m < k; ++m) {
            float4 e = ep[(size_t)m * S4];
            y.x = dC * y.x + e.x;
            y.y = dC * y.y + e.y;
            y.z = dC * y.z + e.z;
            y.w = dC * y.w + e.w;
        }
    }
#pragma unroll 8
    for (int t = 0; t < CHUNK; ++t) {
        float4 v = xp[(size_t)t * S4];
        ema_step(y, v);
        // NT store: out is never re-read; keep x resident in L3 for this
        // kernel's own read stream.
        __builtin_nontemporal_store(*reinterpret_cast<const f32x4*>(&y),
                                    reinterpret_cast<f32x4*>(op + (size_t)t * S4));
    }
}

// Exact but slow fallback if ws is too small (one block per batch).
__global__ __launch_bounds__(TPB) void ema_seq_kernel(const float* __restrict__ x,
                                                      float* __restrict__ out) {
    const int b = blockIdx.x;
    const int tid = threadIdx.x;
    const float4* xp = reinterpret_cast<const float4*>(x) + (size_t)b * T * S4 + tid;
    float4* op = reinterpret_cast<float4*>(out) + (size_t)b * T * S4 + tid;
    float4 y = xp[0];
    for (int t = 0; t < T; ++t) {
        float4 v = xp[(size_t)t * S4];
        ema_step(y, v);
        op[(size_t)t * S4] = y;
    }
}

extern "C" void kernel_launch(void* const* d_in, const int* in_sizes, int n_in,
                              void* d_out, int out_size, void* d_ws, size_t ws_size,
                              hipStream_t stream) {
    (void)in_sizes; (void)n_in; (void)out_size;
    const float* x = reinterpret_cast<const float*>(d_in[0]);
    float* out = reinterpret_cast<float*>(d_out);

    const size_t need = (size_t)B * K * C * sizeof(float);  // 2 MB
    if (ws_size >= need) {
        float* ends = reinterpret_cast<float*>(d_ws);
        const float dC = (float)pow((double)DECAY, (double)CHUNK);
        ema_ends<<<dim3(K, B), dim3(TPB), 0, stream>>>(x, ends);
        ema_fold_apply<<<dim3(K, B), dim3(TPB), 0, stream>>>(x, ends, out, dC);
    } else {
        ema_seq_kernel<<<dim3(B), dim3(TPB), 0, stream>>>(x, out);
    }
}